// Round 6
// baseline (678.527 us; speedup 1.0000x reference)
//
#include <hip/hip_runtime.h>

#define TN 25
#define BN 4096
#define LN 512
#define NEG_INF (-__builtin_huge_valf())

#define SWZF(x, imm) __int_as_float(__builtin_amdgcn_ds_swizzle(__float_as_int(x), (imm)))
#define SWZI(x, imm) __builtin_amdgcn_ds_swizzle((x), (imm))

// ---- 32-lane (half-wave) butterfly reductions via ds_swizzle (imm = xor<<10 | 0x1f) ----
__device__ __forceinline__ float gmax32(float x) {
  x = fmaxf(x, SWZF(x, 0x041F));
  x = fmaxf(x, SWZF(x, 0x081F));
  x = fmaxf(x, SWZF(x, 0x101F));
  x = fmaxf(x, SWZF(x, 0x201F));
  x = fmaxf(x, SWZF(x, 0x401F));
  return x;
}
__device__ __forceinline__ float gsum32(float x) {
  x = x + SWZF(x, 0x041F);
  x = x + SWZF(x, 0x081F);
  x = x + SWZF(x, 0x101F);
  x = x + SWZF(x, 0x201F);
  x = x + SWZF(x, 0x401F);
  return x;
}

// ==================== kernel 1: one batch per wave64, p-range split across halves ====================
// Block = 512 threads = 8 waves. Waves 0-3: Viterbi for batches base+0..3; waves 4-7: forward
// (log-partition + gold numerator) for the same batches. Within a wave, half 0 (lanes 0-31,
// state j = lane) evaluates prev p=0..11, half 1 (lanes 32-63, state j = lane-32) evaluates
// p=12..24; one ds_swizzle(xor32) merge combines. 8192 waves total -> 8 waves/SIMD.
__global__ __launch_bounds__(512, 8) void crf_main(
    const float* __restrict__ emis, const int* __restrict__ tags,
    const float* __restrict__ trans, const float* __restrict__ startT,
    const float* __restrict__ endT, float* __restrict__ nll_out,
    unsigned char* __restrict__ hist, unsigned char* __restrict__ mmap,
    int* __restrict__ lastTagOut) {
  __shared__ float ltr[TN * TN];        // trans[p][j] row-major (numerator gather)
  __shared__ float ltrT[TN][36];        // ltrT[j][p] = trans[p][j]; stride 36 floats (16B-mult)
  __shared__ float sv[8][32];           // per-wave state-vector exchange row

  const int tid = threadIdx.x;
  for (int i = tid; i < TN * TN; i += 512) {
    float v = trans[i];
    ltr[i] = v;
    ltrT[i % TN][i / TN] = v;
  }
  __syncthreads();

  const int wave = tid >> 6;
  const int lane = tid & 63;
  const int h = lane >> 5;                  // half id: 0 -> p 0..11, 1 -> p 12..24
  const int j = lane & 31;                  // owned state
  const int b = blockIdx.x * 4 + (wave & 3);
  const bool act = (j < TN);
  const int jj = act ? j : 0;
  const int pbase = h ? 12 : 0;
  const float endv = act ? endT[j] : NEG_INF;
  const float* emp = emis + (size_t)b * TN;
  const float em0 = act ? emp[j] : 0.0f;
  const float startv = act ? startT[j] : NEG_INF;
  float* svp = sv[wave];

  // 13-slot transition column for this (j, half); h0 slot 12 = -inf pad
  float tcv[13];
  {
    const float4 a = *(const float4*)&ltrT[jj][pbase];
    const float4 c = *(const float4*)&ltrT[jj][pbase + 4];
    const float4 d = *(const float4*)&ltrT[jj][pbase + 8];
    tcv[0] = a.x; tcv[1] = a.y; tcv[2] = a.z; tcv[3] = a.w;
    tcv[4] = c.x; tcv[5] = c.y; tcv[6] = c.z; tcv[7] = c.w;
    tcv[8] = d.x; tcv[9] = d.y; tcv[10] = d.z; tcv[11] = d.w;
    tcv[12] = h ? ltrT[jj][24] : NEG_INF;
  }

  if (wave < 4) {
    // ---------------- Viterbi role ----------------
    float score = startv + em0;               // exact: fl(start + em)
    if (h == 0 && act) svp[j] = score;
    int M = j;                                // chunk-composed backpointer map (h0 meaningful)
    unsigned char* hp = hist + ((size_t)BN + b) * 32 + j;

#pragma unroll 1
    for (int t = 1; t < LN; ++t) {
      emp += (size_t)BN * TN;
      float em = act ? emp[j] : 0.0f;

      // 13 prev scores for this half's p-range (broadcast reads; same-wave in-order w/ write)
      const float4 a = *(const float4*)&svp[pbase];
      const float4 c = *(const float4*)&svp[pbase + 4];
      const float4 d = *(const float4*)&svp[pbase + 8];
      const float sp12 = svp[pbase + 12];

      float v[13]; int ix[13];
      v[0] = (a.x + tcv[0]) + em;  v[1] = (a.y + tcv[1]) + em;
      v[2] = (a.z + tcv[2]) + em;  v[3] = (a.w + tcv[3]) + em;
      v[4] = (c.x + tcv[4]) + em;  v[5] = (c.y + tcv[5]) + em;
      v[6] = (c.z + tcv[6]) + em;  v[7] = (c.w + tcv[7]) + em;
      v[8] = (d.x + tcv[8]) + em;  v[9] = (d.y + tcv[9]) + em;
      v[10] = (d.z + tcv[10]) + em; v[11] = (d.w + tcv[11]) + em;
      v[12] = (sp12 + tcv[12]) + em;         // h0: -inf pad, never wins
#pragma unroll
      for (int k = 0; k < 13; ++k) ix[k] = pbase + k;

      // left-biased tournament over 13 (strict '>' right) == first-max-wins within half
#pragma unroll
      for (int s = 1; s < 13; s <<= 1) {
#pragma unroll
        for (int i2 = 0; i2 + s < 13; i2 += 2 * s) {
          bool g = v[i2 + s] > v[i2];
          v[i2] = g ? v[i2 + s] : v[i2];
          ix[i2] = g ? ix[i2 + s] : ix[i2];
        }
      }

      // cross-half merge: h1 wins only if strictly greater (h0 owns lower p's)
      float vo = SWZF(v[0], 0x401F);
      int go = SWZI(ix[0], 0x401F);
      float vh1 = h ? v[0] : vo, vh0 = h ? vo : v[0];
      int gh1 = h ? ix[0] : go, gh0 = h ? go : ix[0];
      bool better = vh1 > vh0;
      score = better ? vh1 : vh0;
      int barg = better ? gh1 : gh0;

      if (h == 0 && act) svp[j] = score;      // publish for next step
      if (h == 0 && act) *hp = (unsigned char)barg;
      hp += (size_t)BN * 32;

      M = __builtin_amdgcn_ds_bpermute((barg & 31) << 2, M);  // h0 lanes: compose map
      if ((t & 31) == 0) {
        int c2 = (t >> 5) - 1;
        if (h == 0 && act) mmap[((size_t)c2 * BN + b) * 32 + j] = (unsigned char)M;
        M = j;
      }
    }
    if (h == 0 && act) mmap[((size_t)15 * BN + b) * 32 + j] = (unsigned char)M;

    // last tag: argmax_j (score + end), first-max-wins bitwise
    float vv = score + endv;                  // -inf on inactive lanes
    float mv = gmax32(vv);
    unsigned long long bal = __ballot(vv == mv);
    unsigned int gb = (unsigned int)(bal >> (lane & 32));
    int lt = __ffs(gb) - 1;
    if (lane == 0) lastTagOut[b] = lt;
  } else {
    // ---------------- forward (log-partition) + gold-path numerator role ----------------
    float ecv[13];
#pragma unroll
    for (int k = 0; k < 13; ++k) ecv[k] = __expf(tcv[k]);  // h0 slot12: exp(-inf)=0

    int ptag = tags[b];
    float alpha = startv + em0;               // -inf on inactive lanes
    float num_acc = (act && j == ptag) ? alpha : 0.0f;

#pragma unroll 1
    for (int t = 1; t < LN; ++t) {
      emp += (size_t)BN * TN;
      float em = act ? emp[j] : 0.0f;
      int tg = tags[(size_t)t * BN + b];

      // normalizer: state-0 alpha broadcast (spread small; NLL slack huge)
      float mA = SWZF(alpha, 0x0000);
      float ea = __expf(alpha - mA);          // 0 on inactive lanes
      if (h == 0 && act) svp[j] = ea;

      const float4 a = *(const float4*)&svp[pbase];
      const float4 c = *(const float4*)&svp[pbase + 4];
      const float4 d = *(const float4*)&svp[pbase + 8];
      const float ep12 = svp[pbase + 12];

      float s0 = a.x * ecv[0];
      float s1 = a.y * ecv[1];
      s0 = fmaf(a.z, ecv[2], s0);  s1 = fmaf(a.w, ecv[3], s1);
      s0 = fmaf(c.x, ecv[4], s0);  s1 = fmaf(c.y, ecv[5], s1);
      s0 = fmaf(c.z, ecv[6], s0);  s1 = fmaf(c.w, ecv[7], s1);
      s0 = fmaf(d.x, ecv[8], s0);  s1 = fmaf(d.y, ecv[9], s1);
      s0 = fmaf(d.z, ecv[10], s0); s1 = fmaf(d.w, ecv[11], s1);
      s0 = fmaf(ep12, ecv[12], s0);
      float s = s0 + s1;
      float tot = s + SWZF(s, 0x401F);        // cross-half partial-sum merge

      alpha = act ? (__logf(tot) + mA + em) : NEG_INF;

      float trc = ltr[ptag * TN + jj];
      num_acc += (act && j == tg) ? (trc + em) : 0.0f;
      ptag = tg;
    }

    num_acc += (act && j == ptag) ? endv : 0.0f;   // end_transitions[gold last tag]
    float numerator = gsum32(num_acc);

    float va = alpha + endv;
    float m2 = gmax32(va);
    float ssum = gsum32(__expf(va - m2));
    float logZ = __logf(ssum) + m2;

    if (lane == 0) atomicAdd(nll_out, (logZ - numerator) * (1.0f / BN));
  }
}

// ============================ kernel 2: chunk-boundary states ============================
__global__ void crf_bstate(const unsigned char* __restrict__ mmap,
                           const int* __restrict__ lastTag,
                           int* __restrict__ estate) {
  int b = blockIdx.x * 256 + threadIdx.x;
  if (b >= BN) return;
  int s = lastTag[b];
  estate[15 * BN + b] = s;
#pragma unroll
  for (int c = 15; c >= 1; --c) {
    s = mmap[((size_t)c * BN + b) * 32 + s];
    estate[(c - 1) * BN + b] = s;
  }
}

// ============================ kernel 3: per-chunk parallel backtrack ============================
__global__ void crf_backtrack(const unsigned char* __restrict__ hist,
                              const int* __restrict__ estate,
                              float* __restrict__ path) {
  int b = blockIdx.x * 256 + threadIdx.x;
  int c = blockIdx.y;
  int s = estate[c * BN + b];
  int te = (c == 15) ? (LN - 1) : 32 * (c + 1);
  for (int t = te; t > 32 * c; --t) {
    path[(size_t)t * BN + b] = (float)s;
    s = hist[((size_t)t * BN + b) * 32 + s];
  }
  if (c == 0) path[b] = (float)s;
}

extern "C" void kernel_launch(void* const* d_in, const int* in_sizes, int n_in,
                              void* d_out, int out_size, void* d_ws, size_t ws_size,
                              hipStream_t stream) {
  const float* emis   = (const float*)d_in[0];
  const int*   tags   = (const int*)d_in[1];
  const float* trans  = (const float*)d_in[2];
  const float* startT = (const float*)d_in[3];
  const float* endT   = (const float*)d_in[4];
  float* out = (float*)d_out;

  unsigned char* hist = (unsigned char*)d_ws;                 // [512][4096][32] u8 = 64 MiB
  unsigned char* mmap = hist + (size_t)LN * BN * 32;          // [16][4096][32]  u8 =  2 MiB
  int* lastTag = (int*)(mmap + (size_t)16 * BN * 32);         // [4096] i32
  int* estate  = lastTag + BN;                                // [16][4096] i32

  hipMemsetAsync(d_out, 0, sizeof(float), stream);            // zero the NLL accumulator

  crf_main<<<dim3(BN / 4), 512, 0, stream>>>(emis, tags, trans, startT, endT,
                                             out, hist, mmap, lastTag);
  crf_bstate<<<dim3(BN / 256), 256, 0, stream>>>(mmap, lastTag, estate);
  crf_backtrack<<<dim3(BN / 256, 16), 256, 0, stream>>>(hist, estate, out + 1);
}

// Round 7
// 555.102 us; speedup vs baseline: 1.2223x; 1.2223x over previous
//
#include <hip/hip_runtime.h>

#define TN 25
#define BN 4096
#define LN 512
#define NVB 512   // number of viterbi blocks (8 batches each); same count of forward blocks
#define NEG_INF (-__builtin_huge_valf())

#define SWZF(x, imm) __int_as_float(__builtin_amdgcn_ds_swizzle(__float_as_int(x), (imm)))

// ---- 32-lane (half-wave) butterfly reductions via ds_swizzle (imm = xor<<10 | 0x1f) ----
__device__ __forceinline__ float gmax32(float x) {
  x = fmaxf(x, SWZF(x, 0x041F));
  x = fmaxf(x, SWZF(x, 0x081F));
  x = fmaxf(x, SWZF(x, 0x101F));
  x = fmaxf(x, SWZF(x, 0x201F));
  x = fmaxf(x, SWZF(x, 0x401F));
  return x;
}
__device__ __forceinline__ float gsum32(float x) {
  x = x + SWZF(x, 0x041F);
  x = x + SWZF(x, 0x081F);
  x = x + SWZF(x, 0x101F);
  x = x + SWZF(x, 0x201F);
  x = x + SWZF(x, 0x401F);
  return x;
}

// read a 25-float vector from LDS via 6x b128 + 1x b32 (uniform addr per group = broadcast)
__device__ __forceinline__ void read_vec25(const float* __restrict__ p, float (&o)[TN]) {
  const float4 q0 = *(const float4*)(p + 0);
  const float4 q1 = *(const float4*)(p + 4);
  const float4 q2 = *(const float4*)(p + 8);
  const float4 q3 = *(const float4*)(p + 12);
  const float4 q4 = *(const float4*)(p + 16);
  const float4 q5 = *(const float4*)(p + 20);
  o[0]=q0.x;  o[1]=q0.y;  o[2]=q0.z;  o[3]=q0.w;
  o[4]=q1.x;  o[5]=q1.y;  o[6]=q1.z;  o[7]=q1.w;
  o[8]=q2.x;  o[9]=q2.y;  o[10]=q2.z; o[11]=q2.w;
  o[12]=q3.x; o[13]=q3.y; o[14]=q3.z; o[15]=q3.w;
  o[16]=q4.x; o[17]=q4.y; o[18]=q4.z; o[19]=q4.w;
  o[20]=q5.x; o[21]=q5.y; o[22]=q5.z; o[23]=q5.w;
  o[24]=p[24];
}

// 3-way first-max-wins merge (requires ia < ib < ic): max3 + 2 cmp + 2 sel
__device__ __forceinline__ void merge3(float va, int ia, float vb, int ib, float vc, int ic,
                                       float& mo, int& io) {
  float m = fmaxf(fmaxf(va, vb), vc);     // clang fuses to v_max3_f32
  io = (m == va) ? ia : ((m == vb) ? ib : ic);
  mo = m;
}

// ==================== kernel 1: role-PURE blocks — vit blocks + fwd blocks in one grid ===========
// Block = 256 threads = 8 half-wave groups, one batch per group (lane j = state).
// blockIdx.x <  NVB : Viterbi for batches bx*8+grp.
// blockIdx.x >= NVB : forward (log-partition) + gold numerator for batches (bx-NVB)*8+grp.
// Role-pure blocks retire independently; launch_bounds(256,8) -> up to 8 waves/SIMD resident.
__global__ __launch_bounds__(256, 8) void crf_main(
    const float* __restrict__ emis, const int* __restrict__ tags,
    const float* __restrict__ trans, const float* __restrict__ startT,
    const float* __restrict__ endT, float* __restrict__ nll_out,
    unsigned char* __restrict__ hist, unsigned char* __restrict__ mmap,
    int* __restrict__ lastTagOut) {
  __shared__ float ltr[TN * TN];        // trans[p][j] row-major (numerator gather)
  __shared__ float ltrT[TN][28];        // ltrT[j][p] = trans[p][j] (16B-aligned rows)
  __shared__ float eltrT[TN][28];       // exp(trans[p][j]) transposed (so remat never re-runs exp)
  __shared__ float sv[8][32];           // per-group state-vector exchange row

  const int tid = threadIdx.x;
  for (int i = tid; i < TN * TN; i += 256) {
    float v = trans[i];
    ltr[i] = v;
    ltrT[i % TN][i / TN] = v;
    eltrT[i % TN][i / TN] = __expf(v);
  }
  __syncthreads();

  const int j = tid & 31;                   // owned state
  const int grp = tid >> 5;                 // 0..7: batch slot in block
  const bool act = (j < TN);
  const int jj = act ? j : 0;
  const float endv = act ? endT[j] : NEG_INF;
  float* svp = sv[grp];

  if (blockIdx.x < NVB) {
    // ---------------- Viterbi role ----------------
    const int b = blockIdx.x * 8 + grp;
    const float* emp = emis + (size_t)b * TN;
    const float em0 = act ? emp[j] : 0.0f;
    const float startv = act ? startT[j] : NEG_INF;

    float tc[TN];
    read_vec25(&ltrT[jj][0], tc);           // per-lane column; compiler may remat from LDS

    float score = startv + em0;             // exact: fl(start + em)
    if (act) svp[j] = score;
    int M = j;                              // chunk-composed backpointer map
    const int bp_base = (tid & 32) << 2;    // ds_bpermute byte base of this 32-group
    unsigned char* hp = hist + ((size_t)BN + b) * 32 + j;

#pragma unroll 1
    for (int t = 1; t < LN; ++t) {
      emp += (size_t)BN * TN;
      float em = act ? emp[j] : 0.0f;

      float sp[TN];
      read_vec25(svp, sp);                  // previous scores (same-wave in-order DS)

      // candidates WITHOUT em (monotone add: max & value bitwise-safe; em applied once at end)
      float v[TN];
#pragma unroll
      for (int p = 0; p < TN; ++p) v[p] = sp[p] + tc[p];

      // 25-way first-max-wins argmax via 3-way merges (ascending index order maintained)
      float w[9]; int wi[9];
#pragma unroll
      for (int g = 0; g < 8; ++g)
        merge3(v[3*g], 3*g, v[3*g+1], 3*g+1, v[3*g+2], 3*g+2, w[g], wi[g]);
      w[8] = v[24]; wi[8] = 24;
      float u0, u1, u2; int x0, x1, x2;
      merge3(w[0], wi[0], w[1], wi[1], w[2], wi[2], u0, x0);
      merge3(w[3], wi[3], w[4], wi[4], w[5], wi[5], u1, x1);
      merge3(w[6], wi[6], w[7], wi[7], w[8], wi[8], u2, x2);
      float best; int barg;
      merge3(u0, x0, u1, x1, u2, x2, best, barg);

      score = best + em;                    // bitwise == ref (monotone FP add commutes w/ max)

      if (act) svp[j] = score;              // publish for next step
      if (act) *hp = (unsigned char)barg;
      hp += (size_t)BN * 32;

      M = __builtin_amdgcn_ds_bpermute(bp_base + (barg << 2), M);
      if ((t & 31) == 0) {
        int c2 = (t >> 5) - 1;
        if (act) mmap[((size_t)c2 * BN + b) * 32 + j] = (unsigned char)M;
        M = j;
      }
    }
    if (act) mmap[((size_t)15 * BN + b) * 32 + j] = (unsigned char)M;

    // last tag: argmax_j (score + end), first-max-wins bitwise
    float vv = score + endv;                // -inf on inactive lanes
    float mv = gmax32(vv);
    unsigned long long bal = __ballot(vv == mv);
    unsigned int gb = (unsigned int)(bal >> (tid & 32));
    int lt = __ffs(gb) - 1;
    if (j == 0) lastTagOut[b] = lt;
  } else {
    // ---------------- forward (log-partition) + gold-path numerator role ----------------
    const int b = (blockIdx.x - NVB) * 8 + grp;
    const float* emp = emis + (size_t)b * TN;
    const float em0 = act ? emp[j] : 0.0f;
    const float startv = act ? startT[j] : NEG_INF;

    float ec[TN];
    read_vec25(&eltrT[jj][0], ec);          // exp(column); remat = LDS re-read, never re-exp

    int ptag = tags[b];
    float alpha = startv + em0;             // -inf on inactive lanes
    float num_acc = (act && j == ptag) ? alpha : 0.0f;

#pragma unroll 1
    for (int t = 1; t < LN; ++t) {
      emp += (size_t)BN * TN;
      float em = act ? emp[j] : 0.0f;
      int tg = tags[(size_t)t * BN + b];

      // normalizer: state-0 alpha broadcast (spread small; NLL slack is huge)
      float mA = SWZF(alpha, 0x0000);
      float ea = __expf(alpha - mA);        // 0 on inactive lanes
      if (act) svp[j] = ea;                 // publish (same wave -> in-order, no barrier)

      float ep[TN];
      read_vec25(svp, ep);

      float s0 = ep[0] * ec[0];
      float s1 = ep[1] * ec[1];
#pragma unroll
      for (int p = 2; p < TN; p += 2) s0 = fmaf(ep[p], ec[p], s0);
#pragma unroll
      for (int p = 3; p < TN; p += 2) s1 = fmaf(ep[p], ec[p], s1);
      alpha = act ? (__logf(s0 + s1) + mA + em) : NEG_INF;

      float trc = ltr[ptag * TN + jj];
      num_acc += (act && j == tg) ? (trc + em) : 0.0f;
      ptag = tg;
    }

    num_acc += (act && j == ptag) ? endv : 0.0f;   // end_transitions[gold last tag]
    float numerator = gsum32(num_acc);

    float va = alpha + endv;
    float m2 = gmax32(va);
    float ssum = gsum32(__expf(va - m2));
    float logZ = __logf(ssum) + m2;

    if (j == 0) atomicAdd(nll_out, (logZ - numerator) * (1.0f / BN));
  }
}

// ============================ kernel 2: chunk-boundary states ============================
__global__ void crf_bstate(const unsigned char* __restrict__ mmap,
                           const int* __restrict__ lastTag,
                           int* __restrict__ estate) {
  int b = blockIdx.x * 256 + threadIdx.x;
  if (b >= BN) return;
  int s = lastTag[b];
  estate[15 * BN + b] = s;
#pragma unroll
  for (int c = 15; c >= 1; --c) {
    s = mmap[((size_t)c * BN + b) * 32 + s];
    estate[(c - 1) * BN + b] = s;
  }
}

// ============================ kernel 3: per-chunk parallel backtrack ============================
__global__ void crf_backtrack(const unsigned char* __restrict__ hist,
                              const int* __restrict__ estate,
                              float* __restrict__ path) {
  int b = blockIdx.x * 256 + threadIdx.x;
  int c = blockIdx.y;
  int s = estate[c * BN + b];
  int te = (c == 15) ? (LN - 1) : 32 * (c + 1);
  for (int t = te; t > 32 * c; --t) {
    path[(size_t)t * BN + b] = (float)s;
    s = hist[((size_t)t * BN + b) * 32 + s];
  }
  if (c == 0) path[b] = (float)s;
}

extern "C" void kernel_launch(void* const* d_in, const int* in_sizes, int n_in,
                              void* d_out, int out_size, void* d_ws, size_t ws_size,
                              hipStream_t stream) {
  const float* emis   = (const float*)d_in[0];
  const int*   tags   = (const int*)d_in[1];
  const float* trans  = (const float*)d_in[2];
  const float* startT = (const float*)d_in[3];
  const float* endT   = (const float*)d_in[4];
  float* out = (float*)d_out;

  unsigned char* hist = (unsigned char*)d_ws;                 // [512][4096][32] u8 = 64 MiB
  unsigned char* mmap = hist + (size_t)LN * BN * 32;          // [16][4096][32]  u8 =  2 MiB
  int* lastTag = (int*)(mmap + (size_t)16 * BN * 32);         // [4096] i32
  int* estate  = lastTag + BN;                                // [16][4096] i32

  hipMemsetAsync(d_out, 0, sizeof(float), stream);            // zero the NLL accumulator

  crf_main<<<dim3(2 * NVB), 256, 0, stream>>>(emis, tags, trans, startT, endT,
                                              out, hist, mmap, lastTag);
  crf_bstate<<<dim3(BN / 256), 256, 0, stream>>>(mmap, lastTag, estate);
  crf_backtrack<<<dim3(BN / 256, 16), 256, 0, stream>>>(hist, estate, out + 1);
}